// Round 1
// baseline (1098.215 us; speedup 1.0000x reference)
//
#include <hip/hip_runtime.h>
#include <hip/hip_bf16.h>

#define B_   4
#define C_   1024
#define CI_  512
#define NSP_ 2048   // T*H*W = 8*16*16
#define EPS_ 1e-5f

// ---------------- generic 128x128 fp32 tiled GEMM ----------------
// C[M x N] = A * B (+bias per output row)
// TRANS_A: A stored as K x M (row-major, lda = M); else M x K (lda = K)
// TRANS_B: B stored as N x K (row-major, ldb = K); else K x N (ldb = N)
// blockIdx.z = batch; per-operand batch strides (0 for shared weights).
template<bool TRANS_A, bool TRANS_B>
__global__ __launch_bounds__(256)
void gemm128(const float* __restrict__ A, const float* __restrict__ B,
             float* __restrict__ C, const float* __restrict__ bias,
             int M, int N, int K, long sA, long sB, long sC)
{
    __shared__ float As[16][132];
    __shared__ float Bs[16][132];
    const int bz = blockIdx.z;
    A += (long)bz * sA;
    B += (long)bz * sB;
    C += (long)bz * sC;
    const int m0 = blockIdx.y * 128;
    const int n0 = blockIdx.x * 128;
    const int tid = threadIdx.x;
    const int tm = tid >> 4;   // 0..15
    const int tn = tid & 15;   // 0..15

    float acc[2][2][4][4];
    #pragma unroll
    for (int r = 0; r < 2; ++r)
        #pragma unroll
        for (int c = 0; c < 2; ++c)
            #pragma unroll
            for (int i = 0; i < 4; ++i)
                #pragma unroll
                for (int j = 0; j < 4; ++j)
                    acc[r][c][i][j] = 0.f;

    for (int k0 = 0; k0 < K; k0 += 16) {
        // ---- load A tile into As[kk][m] ----
        if (TRANS_A) {
            const int kk = tid >> 4;
            const int mm = (tid & 15) << 2;
            const float* s = A + (long)(k0 + kk) * M + m0 + mm;
            *(float4*)&As[kk][mm]      = *(const float4*)(s);
            *(float4*)&As[kk][mm + 64] = *(const float4*)(s + 64);
        } else {
            const int mm = tid >> 1;
            const int kb = (tid & 1) << 3;
            const float* s = A + (long)(m0 + mm) * K + k0 + kb;
            float4 v0 = *(const float4*)(s);
            float4 v1 = *(const float4*)(s + 4);
            As[kb + 0][mm] = v0.x; As[kb + 1][mm] = v0.y;
            As[kb + 2][mm] = v0.z; As[kb + 3][mm] = v0.w;
            As[kb + 4][mm] = v1.x; As[kb + 5][mm] = v1.y;
            As[kb + 6][mm] = v1.z; As[kb + 7][mm] = v1.w;
        }
        // ---- load B tile into Bs[kk][n] ----
        if (!TRANS_B) {
            const int kk = tid >> 4;
            const int nn = (tid & 15) << 2;
            const float* s = B + (long)(k0 + kk) * N + n0 + nn;
            *(float4*)&Bs[kk][nn]      = *(const float4*)(s);
            *(float4*)&Bs[kk][nn + 64] = *(const float4*)(s + 64);
        } else {
            const int nn = tid >> 1;
            const int kb = (tid & 1) << 3;
            const float* s = B + (long)(n0 + nn) * K + k0 + kb;
            float4 v0 = *(const float4*)(s);
            float4 v1 = *(const float4*)(s + 4);
            Bs[kb + 0][nn] = v0.x; Bs[kb + 1][nn] = v0.y;
            Bs[kb + 2][nn] = v0.z; Bs[kb + 3][nn] = v0.w;
            Bs[kb + 4][nn] = v1.x; Bs[kb + 5][nn] = v1.y;
            Bs[kb + 6][nn] = v1.z; Bs[kb + 7][nn] = v1.w;
        }
        __syncthreads();
        #pragma unroll
        for (int kk = 0; kk < 16; ++kk) {
            float a[8], bb[8];
            *(float4*)&a[0]  = *(float4*)&As[kk][tm << 2];
            *(float4*)&a[4]  = *(float4*)&As[kk][(tm << 2) + 64];
            *(float4*)&bb[0] = *(float4*)&Bs[kk][tn << 2];
            *(float4*)&bb[4] = *(float4*)&Bs[kk][(tn << 2) + 64];
            #pragma unroll
            for (int r = 0; r < 2; ++r)
                #pragma unroll
                for (int i = 0; i < 4; ++i)
                    #pragma unroll
                    for (int c = 0; c < 2; ++c)
                        #pragma unroll
                        for (int j = 0; j < 4; ++j)
                            acc[r][c][i][j] += a[r * 4 + i] * bb[c * 4 + j];
        }
        __syncthreads();
    }

    #pragma unroll
    for (int r = 0; r < 2; ++r)
        #pragma unroll
        for (int i = 0; i < 4; ++i) {
            const int row = m0 + (tm << 2) + r * 64 + i;
            const float bv = bias ? bias[row] : 0.f;
            #pragma unroll
            for (int c = 0; c < 2; ++c) {
                float4 o;
                o.x = acc[r][c][i][0] + bv;
                o.y = acc[r][c][i][1] + bv;
                o.z = acc[r][c][i][2] + bv;
                o.w = acc[r][c][i][3] + bv;
                *(float4*)&C[(long)row * N + n0 + (tn << 2) + c * 64] = o;
            }
        }
}

// ---------------- row softmax over rows of length 2048, in place ----------------
__global__ __launch_bounds__(256)
void softmax2048(float* __restrict__ f)
{
    float* p = f + (long)blockIdx.x * NSP_;
    const int tid = threadIdx.x;
    float v[8];
    #pragma unroll
    for (int i = 0; i < 8; ++i) v[i] = p[tid + (i << 8)];
    float mx = v[0];
    #pragma unroll
    for (int i = 1; i < 8; ++i) mx = fmaxf(mx, v[i]);

    __shared__ float red[256];
    red[tid] = mx;
    __syncthreads();
    for (int s = 128; s > 0; s >>= 1) {
        if (tid < s) red[tid] = fmaxf(red[tid], red[tid + s]);
        __syncthreads();
    }
    mx = red[0];
    __syncthreads();

    float sum = 0.f;
    #pragma unroll
    for (int i = 0; i < 8; ++i) { v[i] = __expf(v[i] - mx); sum += v[i]; }
    red[tid] = sum;
    __syncthreads();
    for (int s = 128; s > 0; s >>= 1) {
        if (tid < s) red[tid] += red[tid + s];
        __syncthreads();
    }
    const float inv = 1.f / red[0];
    #pragma unroll
    for (int i = 0; i < 8; ++i) p[tid + (i << 8)] = v[i] * inv;
}

// ---------------- BatchNorm statistics: per channel over (B, NSP) ----------------
__global__ __launch_bounds__(256)
void bn_stats(const float* __restrict__ wy, const float* __restrict__ gamma,
              const float* __restrict__ beta, float* __restrict__ scale,
              float* __restrict__ shift)
{
    const int c = blockIdx.x;
    const int tid = threadIdx.x;
    float s = 0.f, q = 0.f;
    for (int b = 0; b < B_; ++b) {
        const float* p = wy + ((long)b * C_ + c) * NSP_;
        #pragma unroll
        for (int i = 0; i < NSP_ / 256; ++i) {
            const float v = p[tid + (i << 8)];
            s += v; q += v * v;
        }
    }
    __shared__ float rs[256], rq[256];
    rs[tid] = s; rq[tid] = q;
    __syncthreads();
    for (int st = 128; st > 0; st >>= 1) {
        if (tid < st) { rs[tid] += rs[tid + st]; rq[tid] += rq[tid + st]; }
        __syncthreads();
    }
    if (tid == 0) {
        const float inv = 1.f / (float)(B_ * NSP_);
        const float mean = rs[0] * inv;
        const float var  = rq[0] * inv - mean * mean;
        const float sc = rsqrtf(var + EPS_) * gamma[c];
        scale[c] = sc;
        shift[c] = beta[c] - mean * sc;
    }
}

// ---------------- apply BN + residual: out = wy*scale[c] + shift[c] + x ----------------
__global__ __launch_bounds__(256)
void bn_apply(const float* __restrict__ wy, const float* __restrict__ x,
              const float* __restrict__ scale, const float* __restrict__ shift,
              float* __restrict__ out)
{
    const long total4 = (long)B_ * C_ * NSP_ / 4;  // 2,097,152
    for (long i = (long)blockIdx.x * 256 + threadIdx.x; i < total4;
         i += (long)gridDim.x * 256) {
        const int c = (int)((i >> 9) & (C_ - 1));   // NSP_/4 = 512
        const float4 w  = ((const float4*)wy)[i];
        const float4 xv = ((const float4*)x)[i];
        const float sc = scale[c], sh = shift[c];
        float4 o;
        o.x = w.x * sc + sh + xv.x;
        o.y = w.y * sc + sh + xv.y;
        o.z = w.z * sc + sh + xv.z;
        o.w = w.w * sc + sh + xv.w;
        ((float4*)out)[i] = o;
    }
}

extern "C" void kernel_launch(void* const* d_in, const int* in_sizes, int n_in,
                              void* d_out, int out_size, void* d_ws, size_t ws_size,
                              hipStream_t stream)
{
    const float* x     = (const float*)d_in[0];
    const float* g_w   = (const float*)d_in[1];
    const float* g_b   = (const float*)d_in[2];
    const float* th_w  = (const float*)d_in[3];
    const float* th_b  = (const float*)d_in[4];
    const float* ph_w  = (const float*)d_in[5];
    const float* ph_b  = (const float*)d_in[6];
    const float* w_w   = (const float*)d_in[7];
    const float* w_b   = (const float*)d_in[8];
    const float* gamma = (const float*)d_in[9];
    const float* beta  = (const float*)d_in[10];
    float* out = (float*)d_out;
    float* ws  = (float*)d_ws;

    const size_t SZP = (size_t)B_ * CI_ * NSP_;       // 4,194,304 floats
    float* theta = ws;                                //  16 MB
    float* phi   = ws + SZP;                          //  16 MB
    float* g     = ws + 2 * SZP;                      //  16 MB
    float* f     = ws + 3 * SZP;                      //  64 MB (B*NSP*NSP)
    float* y     = theta;                             // reuse (theta dead after f)
    float* wy    = f;                                 // reuse (attn dead after y)
    float* scale = g;                                 // reuse (g dead after y)
    float* shift = g + C_;

    const dim3 blk(256);
    const long sX  = (long)C_ * NSP_;
    const long sP  = (long)CI_ * NSP_;
    const long sF  = (long)NSP_ * NSP_;
    const long sWY = (long)C_ * NSP_;

    // projections: (CI x C) @ (C x NSP) per batch
    const dim3 gp(NSP_ / 128, CI_ / 128, B_);
    gemm128<false, false><<<gp, blk, 0, stream>>>(g_w,  x, g,     g_b,  CI_, NSP_, C_, 0, sX, sP);
    gemm128<false, false><<<gp, blk, 0, stream>>>(th_w, x, theta, th_b, CI_, NSP_, C_, 0, sX, sP);
    gemm128<false, false><<<gp, blk, 0, stream>>>(ph_w, x, phi,   ph_b, CI_, NSP_, C_, 0, sX, sP);

    // f = theta^T @ phi : (NSP x NSP), K = CI
    const dim3 gf(NSP_ / 128, NSP_ / 128, B_);
    gemm128<true, false><<<gf, blk, 0, stream>>>(theta, phi, f, nullptr, NSP_, NSP_, CI_, sP, sP, sF);

    // softmax rows
    softmax2048<<<B_ * NSP_, blk, 0, stream>>>(f);

    // y = g @ attn^T : (CI x NSP), K = NSP
    gemm128<false, true><<<gp, blk, 0, stream>>>(g, f, y, nullptr, CI_, NSP_, NSP_, sP, sF, sP);

    // w_y = w_w @ y : (C x NSP), K = CI
    const dim3 gw(NSP_ / 128, C_ / 128, B_);
    gemm128<false, false><<<gw, blk, 0, stream>>>(w_w, y, wy, w_b, C_, NSP_, CI_, 0, sP, sWY);

    // BN stats + apply + residual
    bn_stats<<<C_, blk, 0, stream>>>(wy, gamma, beta, scale, shift);
    bn_apply<<<2048, blk, 0, stream>>>(wy, x, scale, shift, out);
}

// Round 5
// 374.304 us; speedup vs baseline: 2.9340x; 2.9340x over previous
//
#include <hip/hip_runtime.h>
#include <hip/hip_bf16.h>

#define B_   4
#define C_   1024
#define CI_  512
#define NSP_ 2048   // T*H*W
#define EPS_ 1e-5f

typedef short bf16x8 __attribute__((ext_vector_type(8)));
typedef float f32x4  __attribute__((ext_vector_type(4)));
typedef unsigned short ushort_t;

static __device__ inline ushort_t f2bf(float v) {
    __hip_bfloat16 h = __float2bfloat16(v);
    return *reinterpret_cast<ushort_t*>(&h);
}
static __device__ inline float bf2f(ushort_t h) {
    unsigned u = ((unsigned)h) << 16;
    float f;
    __builtin_memcpy(&f, &u, 4);
    return f;
}

// ---------------- plain TN bf16 MFMA GEMM, 128x128 tile, BK=32 ----------------
// C[M][N] = sum_k A[i][k] * B[j][k]   (A: MxK row-major lda; B: NxK row-major ldb)
template<bool OUT_BF16>
__global__ __launch_bounds__(256, 2)
void gemm_tn(const ushort_t* __restrict__ A, const ushort_t* __restrict__ Bm,
             void* __restrict__ Cout,
             const float* __restrict__ biasM, const float* __restrict__ biasN,
             int N, int K, int lda, int ldb, int ldc,
             long sA, long sB, long sC)
{
    __shared__ ushort_t smA[128 * 32];
    __shared__ ushort_t smB[128 * 32];
    const int bz = blockIdx.z;
    const ushort_t* Ag = A + bz * sA;
    const ushort_t* Bg = Bm + bz * sB;
    const int m0 = blockIdx.y * 128;
    const int n0 = blockIdx.x * 128;
    const int tid  = threadIdx.x;
    const int wave = tid >> 6;
    const int lane = tid & 63;
    const int wm = wave >> 1, wn = wave & 1;
    const int fr = lane & 15;
    const int kg = lane >> 4;

    int offA[2], offB[2];
    #pragma unroll
    for (int t = 0; t < 2; ++t) {
        const int s   = (wave * 2 + t) * 64 + lane;
        const int row = s >> 2;
        const int kc  = s & 3;
        offA[t] = (m0 + row) * lda + kc * 8;
        offB[t] = (n0 + row) * ldb + kc * 8;
    }
    int aoff[4], boff[4];
    #pragma unroll
    for (int i = 0; i < 4; ++i) {
        aoff[i] = (wm * 64 + i * 16 + fr) * 32 + kg * 8;
        boff[i] = (wn * 64 + i * 16 + fr) * 32 + kg * 8;
    }

    f32x4 acc[4][4];
    #pragma unroll
    for (int i = 0; i < 4; ++i)
        #pragma unroll
        for (int j = 0; j < 4; ++j)
            acc[i][j] = (f32x4)0.f;

    for (int k0 = 0; k0 < K; k0 += 32) {
        #pragma unroll
        for (int t = 0; t < 2; ++t) {
            __builtin_amdgcn_global_load_lds(
                (const __attribute__((address_space(1))) void*)(Ag + offA[t] + k0),
                (__attribute__((address_space(3))) void*)(&smA[(wave * 2 + t) * 512]),
                16, 0, 0);
            __builtin_amdgcn_global_load_lds(
                (const __attribute__((address_space(1))) void*)(Bg + offB[t] + k0),
                (__attribute__((address_space(3))) void*)(&smB[(wave * 2 + t) * 512]),
                16, 0, 0);
        }
        __syncthreads();

        bf16x8 aF[4], bF[4];
        #pragma unroll
        for (int i = 0; i < 4; ++i) aF[i] = *(const bf16x8*)&smA[aoff[i]];
        #pragma unroll
        for (int j = 0; j < 4; ++j) bF[j] = *(const bf16x8*)&smB[boff[j]];
        #pragma unroll
        for (int i = 0; i < 4; ++i)
            #pragma unroll
            for (int j = 0; j < 4; ++j)
                acc[i][j] = __builtin_amdgcn_mfma_f32_16x16x32_bf16(aF[i], bF[j], acc[i][j], 0, 0, 0);
        __syncthreads();
    }

    float*    Cf = (float*)Cout + bz * sC;
    ushort_t* Ch = (ushort_t*)Cout + bz * sC;
    #pragma unroll
    for (int i = 0; i < 4; ++i) {
        const int growb = m0 + wm * 64 + i * 16 + kg * 4;
        #pragma unroll
        for (int j = 0; j < 4; ++j) {
            const int gcol = n0 + wn * 64 + j * 16 + fr;
            const float bN = biasN ? biasN[gcol] : 0.f;
            #pragma unroll
            for (int r = 0; r < 4; ++r) {
                const int grow = growb + r;
                float v = acc[i][j][r] + bN + (biasM ? biasM[grow] : 0.f);
                if (OUT_BF16) Ch[(long)grow * ldc + gcol] = f2bf(v);
                else          Cf[(long)grow * ldc + gcol] = v;
            }
        }
    }
}

// ---------------- split-precision TN GEMM: (Ah+Al)·(Bh+Bl)^T, 3 MFMA passes ----------------
// SPLIT_OUT: write hi/lo bf16 pair; else fp32.
template<bool SPLIT_OUT>
__global__ __launch_bounds__(256, 2)
void gemm_tn_split(const ushort_t* __restrict__ Ah, const ushort_t* __restrict__ Al,
                   const ushort_t* __restrict__ Bh, const ushort_t* __restrict__ Bl,
                   void* __restrict__ outHi, ushort_t* __restrict__ outLo,
                   const float* __restrict__ biasN,
                   int N, int K, int lda, int ldb, int ldc,
                   long sA, long sB, long sC)
{
    __shared__ ushort_t sAh[128 * 32];
    __shared__ ushort_t sAl[128 * 32];
    __shared__ ushort_t sBh[128 * 32];
    __shared__ ushort_t sBl[128 * 32];
    const int bz = blockIdx.z;
    const ushort_t* Ahg = Ah + bz * sA;
    const ushort_t* Alg = Al + bz * sA;
    const ushort_t* Bhg = Bh + bz * sB;
    const ushort_t* Blg = Bl + bz * sB;
    const int m0 = blockIdx.y * 128;
    const int n0 = blockIdx.x * 128;
    const int tid  = threadIdx.x;
    const int wave = tid >> 6;
    const int lane = tid & 63;
    const int wm = wave >> 1, wn = wave & 1;
    const int fr = lane & 15;
    const int kg = lane >> 4;

    int offA[2], offB[2];
    #pragma unroll
    for (int t = 0; t < 2; ++t) {
        const int s   = (wave * 2 + t) * 64 + lane;
        const int row = s >> 2;
        const int kc  = s & 3;
        offA[t] = (m0 + row) * lda + kc * 8;
        offB[t] = (n0 + row) * ldb + kc * 8;
    }
    int aoff[4], boff[4];
    #pragma unroll
    for (int i = 0; i < 4; ++i) {
        aoff[i] = (wm * 64 + i * 16 + fr) * 32 + kg * 8;
        boff[i] = (wn * 64 + i * 16 + fr) * 32 + kg * 8;
    }

    f32x4 acc[4][4];
    #pragma unroll
    for (int i = 0; i < 4; ++i)
        #pragma unroll
        for (int j = 0; j < 4; ++j)
            acc[i][j] = (f32x4)0.f;

    for (int k0 = 0; k0 < K; k0 += 32) {
        #pragma unroll
        for (int t = 0; t < 2; ++t) {
            const int dst = (wave * 2 + t) * 512;
            __builtin_amdgcn_global_load_lds(
                (const __attribute__((address_space(1))) void*)(Ahg + offA[t] + k0),
                (__attribute__((address_space(3))) void*)(&sAh[dst]), 16, 0, 0);
            __builtin_amdgcn_global_load_lds(
                (const __attribute__((address_space(1))) void*)(Alg + offA[t] + k0),
                (__attribute__((address_space(3))) void*)(&sAl[dst]), 16, 0, 0);
            __builtin_amdgcn_global_load_lds(
                (const __attribute__((address_space(1))) void*)(Bhg + offB[t] + k0),
                (__attribute__((address_space(3))) void*)(&sBh[dst]), 16, 0, 0);
            __builtin_amdgcn_global_load_lds(
                (const __attribute__((address_space(1))) void*)(Blg + offB[t] + k0),
                (__attribute__((address_space(3))) void*)(&sBl[dst]), 16, 0, 0);
        }
        __syncthreads();

        bf16x8 aH[4], aL[4], bH[4], bL[4];
        #pragma unroll
        for (int i = 0; i < 4; ++i) {
            aH[i] = *(const bf16x8*)&sAh[aoff[i]];
            aL[i] = *(const bf16x8*)&sAl[aoff[i]];
        }
        #pragma unroll
        for (int j = 0; j < 4; ++j) {
            bH[j] = *(const bf16x8*)&sBh[boff[j]];
            bL[j] = *(const bf16x8*)&sBl[boff[j]];
        }
        #pragma unroll
        for (int i = 0; i < 4; ++i)
            #pragma unroll
            for (int j = 0; j < 4; ++j) {
                acc[i][j] = __builtin_amdgcn_mfma_f32_16x16x32_bf16(aH[i], bH[j], acc[i][j], 0, 0, 0);
                acc[i][j] = __builtin_amdgcn_mfma_f32_16x16x32_bf16(aH[i], bL[j], acc[i][j], 0, 0, 0);
                acc[i][j] = __builtin_amdgcn_mfma_f32_16x16x32_bf16(aL[i], bH[j], acc[i][j], 0, 0, 0);
            }
        __syncthreads();
    }

    float*    Of = (float*)outHi + bz * sC;
    ushort_t* Oh = (ushort_t*)outHi + bz * sC;
    ushort_t* Ol = SPLIT_OUT ? (outLo + bz * sC) : nullptr;
    #pragma unroll
    for (int i = 0; i < 4; ++i) {
        const int growb = m0 + wm * 64 + i * 16 + kg * 4;
        #pragma unroll
        for (int j = 0; j < 4; ++j) {
            const int gcol = n0 + wn * 64 + j * 16 + fr;
            const float bN = biasN ? biasN[gcol] : 0.f;
            #pragma unroll
            for (int r = 0; r < 4; ++r) {
                const int grow = growb + r;
                const long idx = (long)grow * ldc + gcol;
                float v = acc[i][j][r] + bN;
                if (SPLIT_OUT) {
                    const ushort_t h = f2bf(v);
                    Oh[idx] = h;
                    Ol[idx] = f2bf(v - bf2f(h));
                } else {
                    Of[idx] = v;
                }
            }
        }
    }
}

// ---------------- transpose + split-convert: x (B,C,N) f32 -> xT hi/lo (B,N,C) ----------------
__global__ __launch_bounds__(256)
void transpose_cvt_split(const float* __restrict__ x,
                         ushort_t* __restrict__ xh, ushort_t* __restrict__ xl)
{
    __shared__ float t[64][65];
    const int b  = blockIdx.z;
    const int n0 = blockIdx.x * 64, c0 = blockIdx.y * 64;
    const float* xp = x + ((long)b * C_ + c0) * NSP_ + n0;
    const long obase = ((long)b * NSP_ + n0) * C_ + c0;
    const int tr = threadIdx.x >> 6;   // 0..3
    const int tc = threadIdx.x & 63;
    #pragma unroll
    for (int i = 0; i < 16; ++i) {
        const int row = tr * 16 + i;            // C direction
        t[row][tc] = xp[(long)row * NSP_ + tc];
    }
    __syncthreads();
    #pragma unroll
    for (int i = 0; i < 16; ++i) {
        const int row = tr * 16 + i;            // N direction
        const float v = t[tc][row];
        const ushort_t h = f2bf(v);
        const long idx = obase + (long)row * C_ + tc;
        xh[idx] = h;
        xl[idx] = f2bf(v - bf2f(h));
    }
}

// ---------------- f32 -> bf16 converts ----------------
struct U4 { ushort_t a, b, c, d; };
__global__ __launch_bounds__(256)
void cvt4(const float* __restrict__ in, ushort_t* __restrict__ out, int n4)
{
    const int i = blockIdx.x * 256 + threadIdx.x;
    if (i < n4) {
        const float4 v = ((const float4*)in)[i];
        U4 u{f2bf(v.x), f2bf(v.y), f2bf(v.z), f2bf(v.w)};
        ((U4*)out)[i] = u;
    }
}

__global__ __launch_bounds__(256)
void cvt4_split(const float* __restrict__ in, ushort_t* __restrict__ oh,
                ushort_t* __restrict__ ol, int n4)
{
    const int i = blockIdx.x * 256 + threadIdx.x;
    if (i < n4) {
        const float4 v = ((const float4*)in)[i];
        U4 uh{f2bf(v.x), f2bf(v.y), f2bf(v.z), f2bf(v.w)};
        U4 ul{f2bf(v.x - bf2f(uh.a)), f2bf(v.y - bf2f(uh.b)),
              f2bf(v.z - bf2f(uh.c)), f2bf(v.w - bf2f(uh.d))};
        ((U4*)oh)[i] = uh;
        ((U4*)ol)[i] = ul;
    }
}

__global__ __launch_bounds__(256)
void concat_bias(const float* __restrict__ a, const float* __restrict__ b, float* __restrict__ o)
{
    const int i = blockIdx.x * 256 + threadIdx.x;
    if (i < CI_)            o[i] = a[i];
    else if (i < 2 * CI_)   o[i] = b[i - CI_];
}

// ---------------- row softmax (2048), f32 in, bf16 out (strided, in-place over f) ----------------
__global__ __launch_bounds__(256)
void softmax2048(const float* __restrict__ f, ushort_t* __restrict__ attn)
{
    const long rid = blockIdx.x;
    const float* p = f + rid * NSP_;
    ushort_t*    o = attn + rid * (2 * NSP_);
    const int tid = threadIdx.x;
    float v[8];
    #pragma unroll
    for (int i = 0; i < 8; ++i) v[i] = p[tid + (i << 8)];
    float mx = v[0];
    #pragma unroll
    for (int i = 1; i < 8; ++i) mx = fmaxf(mx, v[i]);

    __shared__ float red[256];
    red[tid] = mx;
    __syncthreads();
    for (int s = 128; s > 0; s >>= 1) {
        if (tid < s) red[tid] = fmaxf(red[tid], red[tid + s]);
        __syncthreads();
    }
    mx = red[0];
    __syncthreads();

    float sum = 0.f;
    #pragma unroll
    for (int i = 0; i < 8; ++i) { v[i] = __expf(v[i] - mx); sum += v[i]; }
    red[tid] = sum;
    __syncthreads();
    for (int s = 128; s > 0; s >>= 1) {
        if (tid < s) red[tid] += red[tid + s];
        __syncthreads();
    }
    const float inv = 1.f / red[0];
    __syncthreads();
    #pragma unroll
    for (int i = 0; i < 8; ++i) o[tid + (i << 8)] = f2bf(v[i] * inv);
}

// ---------------- BatchNorm stats ----------------
__global__ __launch_bounds__(256)
void bn_stats(const float* __restrict__ wy, const float* __restrict__ gamma,
              const float* __restrict__ beta, float* __restrict__ scale,
              float* __restrict__ shift)
{
    const int c = blockIdx.x;
    const int tid = threadIdx.x;
    float s = 0.f, q = 0.f;
    for (int b = 0; b < B_; ++b) {
        const float* p = wy + ((long)b * C_ + c) * NSP_;
        #pragma unroll
        for (int i = 0; i < NSP_ / 256; ++i) {
            const float v = p[tid + (i << 8)];
            s += v; q += v * v;
        }
    }
    __shared__ float rs[256], rq[256];
    rs[tid] = s; rq[tid] = q;
    __syncthreads();
    for (int st = 128; st > 0; st >>= 1) {
        if (tid < st) { rs[tid] += rs[tid + st]; rq[tid] += rq[tid + st]; }
        __syncthreads();
    }
    if (tid == 0) {
        const float inv = 1.f / (float)(B_ * NSP_);
        const float mean = rs[0] * inv;
        const float var  = rq[0] * inv - mean * mean;
        const float sc = rsqrtf(var + EPS_) * gamma[c];
        scale[c] = sc;
        shift[c] = beta[c] - mean * sc;
    }
}

// ---------------- BN apply + residual ----------------
__global__ __launch_bounds__(256)
void bn_apply(const float* __restrict__ wy, const float* __restrict__ x,
              const float* __restrict__ scale, const float* __restrict__ shift,
              float* __restrict__ out)
{
    const long total4 = (long)B_ * C_ * NSP_ / 4;
    for (long i = (long)blockIdx.x * 256 + threadIdx.x; i < total4;
         i += (long)gridDim.x * 256) {
        const int c = (int)((i >> 9) & (C_ - 1));
        const float4 w  = ((const float4*)wy)[i];
        const float4 xv = ((const float4*)x)[i];
        const float sc = scale[c], sh = shift[c];
        float4 o;
        o.x = w.x * sc + sh + xv.x;
        o.y = w.y * sc + sh + xv.y;
        o.z = w.z * sc + sh + xv.z;
        o.w = w.w * sc + sh + xv.w;
        ((float4*)out)[i] = o;
    }
}

extern "C" void kernel_launch(void* const* d_in, const int* in_sizes, int n_in,
                              void* d_out, int out_size, void* d_ws, size_t ws_size,
                              hipStream_t stream)
{
    const float* x     = (const float*)d_in[0];
    const float* g_w   = (const float*)d_in[1];
    const float* g_b   = (const float*)d_in[2];
    const float* th_w  = (const float*)d_in[3];
    const float* th_b  = (const float*)d_in[4];
    const float* ph_w  = (const float*)d_in[5];
    const float* ph_b  = (const float*)d_in[6];
    const float* w_w   = (const float*)d_in[7];
    const float* w_b   = (const float*)d_in[8];
    const float* gamma = (const float*)d_in[9];
    const float* beta  = (const float*)d_in[10];
    float* out = (float*)d_out;
    char*  ws  = (char*)d_ws;

    // ---- workspace carve (bytes); lifetimes overlaid, total 110,112,768 ----
    ushort_t* xT_hi   = (ushort_t*)(ws + 0);           // 16 MB   [dead after g GEMM]
    ushort_t* xT_lo   = (ushort_t*)(ws + 16777216);    // 16 MB   [dead after thph GEMM]
    ushort_t* tw_hi   = (ushort_t*)(ws + 33554432);    //  2 MB   [dead after thph GEMM]
    ushort_t* tw_lo   = (ushort_t*)(ws + 35651584);    //  2 MB
    ushort_t* g_w_b   = (ushort_t*)(ws + 37748736);    //  1 MB   [dead after g GEMM]
    float*    f       = (float*)   (ws + 0);           // 64 MB   [written step 5, overlays the above]
    float*    wy      = (float*)   (ws + 0);           // 32 MB   [written step 8, overlays f]
    ushort_t* thph_hi = (ushort_t*)(ws + 67108864);    // 16 MB   [dead after f GEMM]
    ushort_t* thph_lo = (ushort_t*)(ws + 83886080);    // 16 MB
    ushort_t* gcn     = (ushort_t*)(ws + 100663296);   //  8 MB
    ushort_t* w_w_b   = (ushort_t*)(ws + 109051904);   //  1 MB   (needed late - outside f region)
    float*    bias_tp = (float*)   (ws + 110100480);
    float*    scale   = (float*)   (ws + 110104576);
    float*    shift   = (float*)   (ws + 110108672);

    ushort_t* y    = thph_hi;              // reuse after f GEMM (8 MB)
    ushort_t* attn = (ushort_t*)f;         // strided bf16 rows inside f

    const dim3 blk(256);

    // 1) x -> xT hi/lo bf16 (transpose + split)
    transpose_cvt_split<<<dim3(NSP_ / 64, C_ / 64, B_), blk, 0, stream>>>(x, xT_hi, xT_lo);

    // 2) weight conversions (theta|phi split; g, w plain)
    cvt4_split<<<512, blk, 0, stream>>>(th_w, tw_hi,          tw_lo,          131072);
    cvt4_split<<<512, blk, 0, stream>>>(ph_w, tw_hi + 524288, tw_lo + 524288, 131072);
    cvt4<<<512, blk, 0, stream>>>(g_w, g_w_b, 131072);
    cvt4<<<512, blk, 0, stream>>>(w_w, w_w_b, 131072);
    concat_bias<<<4, blk, 0, stream>>>(th_b, ph_b, bias_tp);

    // 3) theta|phi (split): (B, N, 1024) hi/lo = xT(hi/lo) . tw(hi/lo)^T + bias
    gemm_tn_split<true><<<dim3(1024 / 128, NSP_ / 128, B_), blk, 0, stream>>>(
        xT_hi, xT_lo, tw_hi, tw_lo, thph_hi, thph_lo, bias_tp,
        1024, C_, C_, C_, 1024, (long)NSP_ * C_, 0, (long)NSP_ * 1024);

    // 4) g (plain): (B, CI, N) = g_w . xT_hi^T + g_b
    gemm_tn<true><<<dim3(NSP_ / 128, CI_ / 128, B_), blk, 0, stream>>>(
        g_w_b, xT_hi, gcn, g_b, nullptr,
        NSP_, C_, C_, C_, NSP_, 0, (long)NSP_ * C_, (long)CI_ * NSP_);

    // 5) f (split, fp32 out): (B, N, N) = theta(hi/lo) . phi(hi/lo)^T
    gemm_tn_split<false><<<dim3(NSP_ / 128, NSP_ / 128, B_), blk, 0, stream>>>(
        thph_hi, thph_lo, thph_hi + CI_, thph_lo + CI_, f, nullptr, nullptr,
        NSP_, CI_, 1024, 1024, NSP_,
        (long)NSP_ * 1024, (long)NSP_ * 1024, (long)NSP_ * NSP_);

    // 6) softmax rows -> attn bf16 (in place, strided)
    softmax2048<<<B_ * NSP_, blk, 0, stream>>>(f, attn);

    // 7) y (plain): (B, N, CI) = attn . gcn^T
    gemm_tn<true><<<dim3(CI_ / 128, NSP_ / 128, B_), blk, 0, stream>>>(
        attn, gcn, y, nullptr, nullptr,
        CI_, NSP_, 2 * NSP_, NSP_, CI_,
        (long)NSP_ * 2 * NSP_, (long)CI_ * NSP_, (long)NSP_ * CI_);

    // 8) w_y (plain, fp32 out): (B, C, N) = w_w . y^T + w_b
    gemm_tn<false><<<dim3(NSP_ / 128, C_ / 128, B_), blk, 0, stream>>>(
        w_w_b, y, wy, w_b, nullptr,
        NSP_, CI_, CI_, CI_, NSP_, 0, (long)NSP_ * CI_, (long)C_ * NSP_);

    // 9) BN + residual
    bn_stats<<<C_, blk, 0, stream>>>(wy, gamma, beta, scale, shift);
    bn_apply<<<2048, blk, 0, stream>>>(wy, x, scale, shift, out);
}

// Round 6
// 320.874 us; speedup vs baseline: 3.4226x; 1.1665x over previous
//
#include <hip/hip_runtime.h>
#include <hip/hip_bf16.h>

#define B_   4
#define C_   1024
#define CI_  512
#define NSP_ 2048   // T*H*W
#define EPS_ 1e-5f

typedef _Float16 f16x8 __attribute__((ext_vector_type(8)));
typedef float f32x4  __attribute__((ext_vector_type(4)));
typedef unsigned short ushort_t;

static __device__ inline ushort_t f2h(float v) {
    _Float16 h = (_Float16)v;
    ushort_t u;
    __builtin_memcpy(&u, &h, 2);
    return u;
}

// ---------------- TN fp16 MFMA GEMM, 128x128 tile, BK=32 ----------------
// C[M][N] = sum_k A[i][k] * B[j][k]   (A: MxK row-major lda; B: NxK row-major ldb)
// fp32 accumulate; OUT_F16 selects output type. biasM per-row / biasN per-col (nullable).
template<bool OUT_F16>
__global__ __launch_bounds__(256, 2)
void gemm_tn(const ushort_t* __restrict__ A, const ushort_t* __restrict__ Bm,
             void* __restrict__ Cout,
             const float* __restrict__ biasM, const float* __restrict__ biasN,
             int N, int K, int lda, int ldb, int ldc,
             long sA, long sB, long sC)
{
    __shared__ ushort_t smA[128 * 32];
    __shared__ ushort_t smB[128 * 32];
    const int bz = blockIdx.z;
    const ushort_t* Ag = A + bz * sA;
    const ushort_t* Bg = Bm + bz * sB;
    const int m0 = blockIdx.y * 128;
    const int n0 = blockIdx.x * 128;
    const int tid  = threadIdx.x;
    const int wave = tid >> 6;
    const int lane = tid & 63;
    const int wm = wave >> 1, wn = wave & 1;
    const int fr = lane & 15;      // fragment row/col within 16
    const int kg = lane >> 4;      // k-group 0..3 (8 k each)

    // staging geometry: 2 chunks of 1KB per wave per operand
    int offA[2], offB[2];
    #pragma unroll
    for (int t = 0; t < 2; ++t) {
        const int s   = (wave * 2 + t) * 64 + lane;  // 16B slot index in tile
        const int row = s >> 2;
        const int kc  = s & 3;
        offA[t] = (m0 + row) * lda + kc * 8;
        offB[t] = (n0 + row) * ldb + kc * 8;
    }
    // LDS fragment read offsets (ushort units)
    int aoff[4], boff[4];
    #pragma unroll
    for (int i = 0; i < 4; ++i) {
        aoff[i] = (wm * 64 + i * 16 + fr) * 32 + kg * 8;
        boff[i] = (wn * 64 + i * 16 + fr) * 32 + kg * 8;
    }

    f32x4 acc[4][4];
    #pragma unroll
    for (int i = 0; i < 4; ++i)
        #pragma unroll
        for (int j = 0; j < 4; ++j)
            acc[i][j] = (f32x4)0.f;

    for (int k0 = 0; k0 < K; k0 += 32) {
        #pragma unroll
        for (int t = 0; t < 2; ++t) {
            __builtin_amdgcn_global_load_lds(
                (const __attribute__((address_space(1))) void*)(Ag + offA[t] + k0),
                (__attribute__((address_space(3))) void*)(&smA[(wave * 2 + t) * 512]),
                16, 0, 0);
            __builtin_amdgcn_global_load_lds(
                (const __attribute__((address_space(1))) void*)(Bg + offB[t] + k0),
                (__attribute__((address_space(3))) void*)(&smB[(wave * 2 + t) * 512]),
                16, 0, 0);
        }
        __syncthreads();   // drains vmcnt -> staged data visible

        f16x8 aF[4], bF[4];
        #pragma unroll
        for (int i = 0; i < 4; ++i) aF[i] = *(const f16x8*)&smA[aoff[i]];
        #pragma unroll
        for (int j = 0; j < 4; ++j) bF[j] = *(const f16x8*)&smB[boff[j]];
        #pragma unroll
        for (int i = 0; i < 4; ++i)
            #pragma unroll
            for (int j = 0; j < 4; ++j)
                acc[i][j] = __builtin_amdgcn_mfma_f32_16x16x32_f16(aF[i], bF[j], acc[i][j], 0, 0, 0);
        __syncthreads();
    }

    // epilogue: D mapping col=lane&15, row=(lane>>4)*4+reg
    float*    Cf = (float*)Cout + bz * sC;
    ushort_t* Ch = (ushort_t*)Cout + bz * sC;
    #pragma unroll
    for (int i = 0; i < 4; ++i) {
        const int growb = m0 + wm * 64 + i * 16 + kg * 4;
        #pragma unroll
        for (int j = 0; j < 4; ++j) {
            const int gcol = n0 + wn * 64 + j * 16 + fr;
            const float bN = biasN ? biasN[gcol] : 0.f;
            #pragma unroll
            for (int r = 0; r < 4; ++r) {
                const int grow = growb + r;
                float v = acc[i][j][r] + bN + (biasM ? biasM[grow] : 0.f);
                if (OUT_F16) Ch[(long)grow * ldc + gcol] = f2h(v);
                else         Cf[(long)grow * ldc + gcol] = v;
            }
        }
    }
}

// ---------------- transpose + convert: x (B,C,N) f32 -> xT (B,N,C) fp16 ----------------
__global__ __launch_bounds__(256)
void transpose_cvt(const float* __restrict__ x, ushort_t* __restrict__ xT)
{
    __shared__ ushort_t t[64][65];
    const int b  = blockIdx.z;
    const int n0 = blockIdx.x * 64, c0 = blockIdx.y * 64;
    const float*  xp = x  + ((long)b * C_ + c0) * NSP_ + n0;
    ushort_t*     op = xT + ((long)b * NSP_ + n0) * C_ + c0;
    const int tr = threadIdx.x >> 6;   // 0..3
    const int tc = threadIdx.x & 63;
    #pragma unroll
    for (int i = 0; i < 16; ++i) {
        const int row = tr * 16 + i;            // C direction
        t[row][tc] = f2h(xp[(long)row * NSP_ + tc]);
    }
    __syncthreads();
    #pragma unroll
    for (int i = 0; i < 16; ++i) {
        const int row = tr * 16 + i;            // N direction
        op[(long)row * C_ + tc] = t[tc][row];
    }
}

// ---------------- f32 -> fp16 convert ----------------
struct U4 { ushort_t a, b, c, d; };
__global__ __launch_bounds__(256)
void cvt4(const float* __restrict__ in, ushort_t* __restrict__ out, int n4)
{
    const int i = blockIdx.x * 256 + threadIdx.x;
    if (i < n4) {
        const float4 v = ((const float4*)in)[i];
        U4 u{f2h(v.x), f2h(v.y), f2h(v.z), f2h(v.w)};
        ((U4*)out)[i] = u;
    }
}

__global__ __launch_bounds__(256)
void concat_bias(const float* __restrict__ a, const float* __restrict__ b, float* __restrict__ o)
{
    const int i = blockIdx.x * 256 + threadIdx.x;
    if (i < CI_)            o[i] = a[i];
    else if (i < 2 * CI_)   o[i] = b[i - CI_];
}

// ---------------- row softmax (2048), f32 in, fp16 out (strided, in-place over f) ----------------
__global__ __launch_bounds__(256)
void softmax2048(const float* __restrict__ f, ushort_t* __restrict__ attn)
{
    const long rid = blockIdx.x;
    const float* p = f + rid * NSP_;
    ushort_t*    o = attn + rid * (2 * NSP_);   // fp16 row inside the fp32 row slot
    const int tid = threadIdx.x;
    float v[8];
    #pragma unroll
    for (int i = 0; i < 8; ++i) v[i] = p[tid + (i << 8)];
    float mx = v[0];
    #pragma unroll
    for (int i = 1; i < 8; ++i) mx = fmaxf(mx, v[i]);

    __shared__ float red[256];
    red[tid] = mx;
    __syncthreads();
    for (int s = 128; s > 0; s >>= 1) {
        if (tid < s) red[tid] = fmaxf(red[tid], red[tid + s]);
        __syncthreads();
    }
    mx = red[0];
    __syncthreads();

    float sum = 0.f;
    #pragma unroll
    for (int i = 0; i < 8; ++i) { v[i] = __expf(v[i] - mx); sum += v[i]; }
    red[tid] = sum;
    __syncthreads();
    for (int s = 128; s > 0; s >>= 1) {
        if (tid < s) red[tid] += red[tid + s];
        __syncthreads();
    }
    const float inv = 1.f / red[0];
    __syncthreads();   // all reads of p done before overwriting (same block only)
    #pragma unroll
    for (int i = 0; i < 8; ++i) o[tid + (i << 8)] = f2h(v[i] * inv);
}

// ---------------- BatchNorm stats ----------------
__global__ __launch_bounds__(256)
void bn_stats(const float* __restrict__ wy, const float* __restrict__ gamma,
              const float* __restrict__ beta, float* __restrict__ scale,
              float* __restrict__ shift)
{
    const int c = blockIdx.x;
    const int tid = threadIdx.x;
    float s = 0.f, q = 0.f;
    for (int b = 0; b < B_; ++b) {
        const float* p = wy + ((long)b * C_ + c) * NSP_;
        #pragma unroll
        for (int i = 0; i < NSP_ / 256; ++i) {
            const float v = p[tid + (i << 8)];
            s += v; q += v * v;
        }
    }
    __shared__ float rs[256], rq[256];
    rs[tid] = s; rq[tid] = q;
    __syncthreads();
    for (int st = 128; st > 0; st >>= 1) {
        if (tid < st) { rs[tid] += rs[tid + st]; rq[tid] += rq[tid + st]; }
        __syncthreads();
    }
    if (tid == 0) {
        const float inv = 1.f / (float)(B_ * NSP_);
        const float mean = rs[0] * inv;
        const float var  = rq[0] * inv - mean * mean;
        const float sc = rsqrtf(var + EPS_) * gamma[c];
        scale[c] = sc;
        shift[c] = beta[c] - mean * sc;
    }
}

// ---------------- BN apply + residual ----------------
__global__ __launch_bounds__(256)
void bn_apply(const float* __restrict__ wy, const float* __restrict__ x,
              const float* __restrict__ scale, const float* __restrict__ shift,
              float* __restrict__ out)
{
    const long total4 = (long)B_ * C_ * NSP_ / 4;
    for (long i = (long)blockIdx.x * 256 + threadIdx.x; i < total4;
         i += (long)gridDim.x * 256) {
        const int c = (int)((i >> 9) & (C_ - 1));
        const float4 w  = ((const float4*)wy)[i];
        const float4 xv = ((const float4*)x)[i];
        const float sc = scale[c], sh = shift[c];
        float4 o;
        o.x = w.x * sc + sh + xv.x;
        o.y = w.y * sc + sh + xv.y;
        o.z = w.z * sc + sh + xv.z;
        o.w = w.w * sc + sh + xv.w;
        ((float4*)out)[i] = o;
    }
}

extern "C" void kernel_launch(void* const* d_in, const int* in_sizes, int n_in,
                              void* d_out, int out_size, void* d_ws, size_t ws_size,
                              hipStream_t stream)
{
    const float* x     = (const float*)d_in[0];
    const float* g_w   = (const float*)d_in[1];
    const float* g_b   = (const float*)d_in[2];
    const float* th_w  = (const float*)d_in[3];
    const float* th_b  = (const float*)d_in[4];
    const float* ph_w  = (const float*)d_in[5];
    const float* ph_b  = (const float*)d_in[6];
    const float* w_w   = (const float*)d_in[7];
    const float* w_b   = (const float*)d_in[8];
    const float* gamma = (const float*)d_in[9];
    const float* beta  = (const float*)d_in[10];
    float* out = (float*)d_out;
    char*  ws  = (char*)d_ws;

    // ---- workspace carve (bytes), total ~108 MB (< proven 113.2 MB) ----
    ushort_t* xT      = (ushort_t*)(ws + 0);           // 16 MB  (B,N,C) fp16
    ushort_t* tw      = (ushort_t*)(ws + 16777216);    //  2 MB  (theta|phi weights, 1024x1024)
    ushort_t* g_w_h   = (ushort_t*)(ws + 18874368);    //  1 MB
    ushort_t* w_w_h   = (ushort_t*)(ws + 19922944);    //  1 MB
    ushort_t* thph    = (ushort_t*)(ws + 20971520);    // 16 MB  (B,N,1024) fp16 ; later y (B,N,CI)
    ushort_t* gcn     = (ushort_t*)(ws + 37748736);    //  8 MB  (B,CI,N) fp16
    float*    f       = (float*)   (ws + 46137344);    // 64 MB  (B,N,N) fp32 ; attn fp16 in-place ; later wy
    float*    bias_tp = (float*)   (ws + 113246208);
    float*    scale   = (float*)   (ws + 113250304);
    float*    shift   = (float*)   (ws + 113254400);

    ushort_t* y    = thph;                 // reuse after f GEMM
    ushort_t* attn = (ushort_t*)f;         // strided fp16 rows inside f
    float*    wy   = f;                    // reuse after y GEMM

    const dim3 blk(256);

    // 1) x -> xT fp16 (transpose)
    transpose_cvt<<<dim3(NSP_ / 64, C_ / 64, B_), blk, 0, stream>>>(x, xT);

    // 2) weight conversions
    cvt4<<<512, blk, 0, stream>>>(th_w, tw,          131072);
    cvt4<<<512, blk, 0, stream>>>(ph_w, tw + 524288, 131072);
    cvt4<<<512, blk, 0, stream>>>(g_w,  g_w_h,       131072);
    cvt4<<<512, blk, 0, stream>>>(w_w,  w_w_h,       131072);
    concat_bias<<<4, blk, 0, stream>>>(th_b, ph_b, bias_tp);

    // 3) theta|phi : (B, N, 1024) = xT (N x C) . tw (1024 x C)^T + bias
    gemm_tn<true><<<dim3(1024 / 128, NSP_ / 128, B_), blk, 0, stream>>>(
        xT, tw, thph, nullptr, bias_tp,
        1024, C_, C_, C_, 1024, (long)NSP_ * C_, 0, (long)NSP_ * 1024);

    // 4) g : (B, CI, N) = g_w (CI x C) . xT (N x C)^T + g_b
    gemm_tn<true><<<dim3(NSP_ / 128, CI_ / 128, B_), blk, 0, stream>>>(
        g_w_h, xT, gcn, g_b, nullptr,
        NSP_, C_, C_, C_, NSP_, 0, (long)NSP_ * C_, (long)CI_ * NSP_);

    // 5) f : (B, N, N) fp32 = theta (N x CI) . phi (N x CI)^T
    gemm_tn<false><<<dim3(NSP_ / 128, NSP_ / 128, B_), blk, 0, stream>>>(
        thph, thph + CI_, f, nullptr, nullptr,
        NSP_, CI_, 1024, 1024, NSP_,
        (long)NSP_ * 1024, (long)NSP_ * 1024, (long)NSP_ * NSP_);

    // 6) softmax rows -> attn fp16 (in place, strided)
    softmax2048<<<B_ * NSP_, blk, 0, stream>>>(f, attn);

    // 7) y : (B, N, CI) = attn (N x N, lda=2N fp16) . gcn (CI x N)^T
    gemm_tn<true><<<dim3(CI_ / 128, NSP_ / 128, B_), blk, 0, stream>>>(
        attn, gcn, y, nullptr, nullptr,
        CI_, NSP_, 2 * NSP_, NSP_, CI_,
        (long)NSP_ * 2 * NSP_, (long)CI_ * NSP_, (long)NSP_ * CI_);

    // 8) w_y : (B, C, N) fp32 = w_w (C x CI) . y (N x CI)^T + w_b
    gemm_tn<false><<<dim3(NSP_ / 128, C_ / 128, B_), blk, 0, stream>>>(
        w_w_h, y, wy, w_b, nullptr,
        NSP_, CI_, CI_, CI_, NSP_, 0, (long)NSP_ * CI_, (long)C_ * NSP_);

    // 9) BN + residual
    bn_stats<<<C_, blk, 0, stream>>>(wy, gamma, beta, scale, shift);
    bn_apply<<<2048, blk, 0, stream>>>(wy, x, scale, shift, out);
}